// Round 3
// baseline (360.607 us; speedup 1.0000x reference)
//
#include <hip/hip_runtime.h>
#include <math.h>

// SpanPairVAHead on MI355X (gfx950).
// Dtype map (established rounds 0-2): ALL float tensors f32, spans int
// (32/64 sniffed on device), OUTPUT f32. Internal activations bf16 for MFMA.
//
// B=64, L=512, H=1024, Q=64, VA_H=256. Pairs = B*Q = 4096.

typedef __attribute__((ext_vector_type(4))) float f32x4;
typedef __attribute__((ext_vector_type(8))) short bf16x8;

#define NPAIR 4096
#define LSEQ 512
#define HDIM 1024

__device__ __forceinline__ unsigned short f2bf(float f) {
  unsigned int x = __float_as_uint(f);
  return (unsigned short)((x + 0x7fffu + ((x >> 16) & 1u)) >> 16);  // RNE
}
__device__ __forceinline__ unsigned int pack2(float lo, float hi) {
  return (unsigned int)f2bf(lo) | ((unsigned int)f2bf(hi) << 16);
}

// ---------------------------------------------------------------------------
// Span decode: sniff int64-vs-int32 layout, invalid span (s<2) -> [SEP]={1},
// masked/empty -> scale 0 with in-range indices.
// ---------------------------------------------------------------------------
__device__ __forceinline__ void load_span(const int* spans, int pair, int qm,
                                          int& s0, int& e0, int& s1, int& e1,
                                          float& sA, float& sO) {
  const bool is64 =
      (spans[1] == 0) && (spans[3] == 0) && (spans[5] == 0) && (spans[7] == 0);
  if (is64) {
    s0 = spans[(pair * 4 + 0) * 2];
    e0 = spans[(pair * 4 + 1) * 2];
    s1 = spans[(pair * 4 + 2) * 2];
    e1 = spans[(pair * 4 + 3) * 2];
  } else {
    s0 = spans[pair * 4 + 0];
    e0 = spans[pair * 4 + 1];
    s1 = spans[pair * 4 + 2];
    e1 = spans[pair * 4 + 3];
  }
  if (s0 < 2) { s0 = 1; e0 = 1; }
  if (s1 < 2) { s1 = 1; e1 = 1; }
  sA = (qm != 0 && e0 >= s0) ? 1.f / (float)(e0 - s0 + 1) : 0.f;
  sO = (qm != 0 && e1 >= s1) ? 1.f / (float)(e1 - s1 + 1) : 0.f;
  if (sA == 0.f) { s0 = 1; e0 = 1; }
  if (sO == 0.f) { s1 = 1; e1 = 1; }
}

// ---------------------------------------------------------------------------
// Cumsum along L: P[b,l,h] = sum_{l'<=l} hs[b,l',h]. Thread-per-column,
// 65536 threads (256 blocks) -> ~4 waves/CU for latency hiding. Coalesced.
// ---------------------------------------------------------------------------
__global__ __launch_bounds__(256) void cumsum_kernel(
    const float* __restrict__ hs, float* __restrict__ P) {
  const int t = blockIdx.x * 256 + threadIdx.x;  // 0..65535
  const int b = t >> 10;                          // batch
  const int c = t & 1023;                         // column
  const float* src = hs + (size_t)b * (LSEQ * HDIM) + c;
  float* dst = P + (size_t)b * (LSEQ * HDIM) + c;
  float acc = 0.f;
#pragma unroll 4
  for (int l = 0; l < LSEQ; ++l) {
    acc += src[(size_t)l * HDIM];
    dst[(size_t)l * HDIM] = acc;
  }
}

// ---------------------------------------------------------------------------
// Pool from prefix sums: one block per pair; thread owns 4 h-elements.
// h_pair[pair] = [h_asp | h_opi | h_asp*h_opi] bf16 (4096 x 3072).
// ---------------------------------------------------------------------------
__global__ __launch_bounds__(256) void pool_from_prefix(
    const float* __restrict__ P, const int* __restrict__ spans,
    const int* __restrict__ qmask, unsigned short* __restrict__ hpair) {
  const int i = blockIdx.x;
  const int xcd = i & 7;
  const int j = i >> 3;
  const int b = xcd * 8 + (j & 7);   // 8 batches per XCD (L2 locality)
  const int q = j >> 3;
  const int pair = b * 64 + q;
  const int tid = threadIdx.x;

  int s0, e0, s1, e1; float sA, sO;
  load_span(spans, pair, qmask[pair], s0, e0, s1, e1, sA, sO);

  const float* Pb = P + (size_t)b * (LSEQ * HDIM) + tid * 4;
  float4 peA = *(const float4*)(Pb + (size_t)e0 * HDIM);
  float4 psA = *(const float4*)(Pb + (size_t)(s0 - 1) * HDIM);
  float4 peO = *(const float4*)(Pb + (size_t)e1 * HDIM);
  float4 psO = *(const float4*)(Pb + (size_t)(s1 - 1) * HDIM);

  const float a0 = (peA.x - psA.x) * sA, a1 = (peA.y - psA.y) * sA;
  const float a2 = (peA.z - psA.z) * sA, a3 = (peA.w - psA.w) * sA;
  const float o0 = (peO.x - psO.x) * sO, o1 = (peO.y - psO.y) * sO;
  const float o2 = (peO.z - psO.z) * sO, o3 = (peO.w - psO.w) * sO;

  unsigned short* dst = hpair + (size_t)pair * 3072 + tid * 4;
  uint2 w;
  w.x = pack2(a0, a1); w.y = pack2(a2, a3);
  *(uint2*)(dst) = w;
  w.x = pack2(o0, o1); w.y = pack2(o2, o3);
  *(uint2*)(dst + 1024) = w;
  w.x = pack2(a0 * o0, a1 * o1); w.y = pack2(a2 * o2, a3 * o3);
  *(uint2*)(dst + 2048) = w;
}

// ---------------------------------------------------------------------------
// Brute-force pooling fallback (workspace too small for prefix array).
// ---------------------------------------------------------------------------
__global__ __launch_bounds__(256) void pool_brute(
    const float* __restrict__ hs, const int* __restrict__ spans,
    const int* __restrict__ qmask, unsigned short* __restrict__ hpair) {
  const int i = blockIdx.x;
  const int xcd = i & 7;
  const int j = i >> 3;
  const int b = xcd * 8 + (j & 7);
  const int q = j >> 3;
  const int pair = b * 64 + q;
  const int tid = threadIdx.x;

  int s0, e0, s1, e1; float sA, sO;
  load_span(spans, pair, qmask[pair], s0, e0, s1, e1, sA, sO);
  if (sA == 0.f) { e0 = s0 - 1; }
  if (sO == 0.f) { e1 = s1 - 1; }

  const float* hb = hs + (size_t)b * (LSEQ * HDIM) + tid * 4;
  float A0 = 0, A1 = 0, A2 = 0, A3 = 0;
  float O0 = 0, O1 = 0, O2 = 0, O3 = 0;
  for (int l = s0; l <= e0; ++l) {
    float4 v = *(const float4*)(hb + (size_t)l * HDIM);
    A0 += v.x; A1 += v.y; A2 += v.z; A3 += v.w;
  }
  for (int l = s1; l <= e1; ++l) {
    float4 v = *(const float4*)(hb + (size_t)l * HDIM);
    O0 += v.x; O1 += v.y; O2 += v.z; O3 += v.w;
  }
  const float a0 = A0 * sA, a1 = A1 * sA, a2 = A2 * sA, a3 = A3 * sA;
  const float o0 = O0 * sO, o1 = O1 * sO, o2 = O2 * sO, o3 = O3 * sO;

  unsigned short* dst = hpair + (size_t)pair * 3072 + tid * 4;
  uint2 w;
  w.x = pack2(a0, a1); w.y = pack2(a2, a3);
  *(uint2*)(dst) = w;
  w.x = pack2(o0, o1); w.y = pack2(o2, o3);
  *(uint2*)(dst + 1024) = w;
  w.x = pack2(a0 * o0, a1 * o1); w.y = pack2(a2 * o2, a3 * o3);
  *(uint2*)(dst + 2048) = w;
}

// ---------------------------------------------------------------------------
// Transpose + f32->bf16 convert: in (R x C) f32 -> out (C x R) bf16.
// ---------------------------------------------------------------------------
__global__ void transpose_f32_bf16(const float* __restrict__ in,
                                   unsigned short* __restrict__ out, int R,
                                   int C) {
  __shared__ float t[32][33];
  const int c0 = blockIdx.x * 32, r0 = blockIdx.y * 32;
  const int x = threadIdx.x, y = threadIdx.y;  // block (32, 8)
#pragma unroll
  for (int i = 0; i < 32; i += 8)
    if (r0 + y + i < R && c0 + x < C)
      t[y + i][x] = in[(size_t)(r0 + y + i) * C + c0 + x];
  __syncthreads();
#pragma unroll
  for (int i = 0; i < 32; i += 8)
    if (c0 + y + i < C && r0 + x < R)
      out[(size_t)(c0 + y + i) * R + r0 + x] = f2bf(t[x][y + i]);
}

// ---------------------------------------------------------------------------
// bf16 MFMA GEMM: C = act(A(MxK) @ Bt(NxK)^T + bias_f32) -> bf16.
// 64x64 tile, BK=32, 4 waves, 2x2 mfma_f32_16x16x32_bf16 per wave.
// ---------------------------------------------------------------------------
template <int ACT>
__global__ __launch_bounds__(256) void gemm_bt_bias_act(
    const unsigned short* __restrict__ A, const unsigned short* __restrict__ Bt,
    const float* __restrict__ bias, unsigned short* __restrict__ C, int M,
    int N, int K) {
  __shared__ __align__(16) unsigned short Al[64][40];
  __shared__ __align__(16) unsigned short Bl[64][40];
  const int bm = blockIdx.x * 64, bn = blockIdx.y * 64;
  const int tid = threadIdx.x;
  const int wave = tid >> 6, lane = tid & 63;
  const int wm = (wave & 1) * 32, wn = (wave >> 1) * 32;
  const int ar = tid >> 2, ac = (tid & 3) * 8;
  const int lm = lane & 15, lk = (lane >> 4) * 8;

  f32x4 acc00 = {0.f, 0.f, 0.f, 0.f}, acc01 = {0.f, 0.f, 0.f, 0.f};
  f32x4 acc10 = {0.f, 0.f, 0.f, 0.f}, acc11 = {0.f, 0.f, 0.f, 0.f};

  const unsigned short* pa = A + (size_t)(bm + ar) * K + ac;
  const unsigned short* pb = Bt + (size_t)(bn + ar) * K + ac;

  for (int k0 = 0; k0 < K; k0 += 32) {
    uint4 va = *(const uint4*)(pa + k0);
    uint4 vb = *(const uint4*)(pb + k0);
    *(uint4*)&Al[ar][ac] = va;
    *(uint4*)&Bl[ar][ac] = vb;
    __syncthreads();
    bf16x8 a0 = *(const bf16x8*)&Al[wm + lm][lk];
    bf16x8 a1 = *(const bf16x8*)&Al[wm + 16 + lm][lk];
    bf16x8 b0 = *(const bf16x8*)&Bl[wn + lm][lk];
    bf16x8 b1 = *(const bf16x8*)&Bl[wn + 16 + lm][lk];
    acc00 = __builtin_amdgcn_mfma_f32_16x16x32_bf16(a0, b0, acc00, 0, 0, 0);
    acc01 = __builtin_amdgcn_mfma_f32_16x16x32_bf16(a0, b1, acc01, 0, 0, 0);
    acc10 = __builtin_amdgcn_mfma_f32_16x16x32_bf16(a1, b0, acc10, 0, 0, 0);
    acc11 = __builtin_amdgcn_mfma_f32_16x16x32_bf16(a1, b1, acc11, 0, 0, 0);
    __syncthreads();
  }

  // C/D layout (m89): col = lane&15, row = (lane>>4)*4 + reg.
  const int r0 = bm + wm + ((lane >> 4) << 2);
  const int c0 = bn + wn + lm;
  const float bs0 = bias[c0];
  const float bs1 = bias[c0 + 16];
  auto emit = [&](f32x4 v, int row0, int col, float bs) {
#pragma unroll
    for (int r = 0; r < 4; ++r) {
      float x = v[r] + bs;
      if (ACT == 1) x = 0.5f * x * (1.f + erff(x * 0.70710678118654752f));
      C[(size_t)(row0 + r) * N + col] = f2bf(x);
    }
  };
  emit(acc00, r0, c0, bs0);
  emit(acc10, r0 + 16, c0, bs0);
  emit(acc01, r0, c0 + 16, bs1);
  emit(acc11, r0 + 16, c0 + 16, bs1);
}

// ---------------------------------------------------------------------------
// Head: x2(4096x128 bf16) @ W3(128x2 f32) + b3 -> sigmoid*8+1 -> *mask -> F32
// ---------------------------------------------------------------------------
__global__ __launch_bounds__(256) void head_kernel(
    const unsigned short* __restrict__ x2, const float* __restrict__ W3,
    const float* __restrict__ b3, const int* __restrict__ qmask,
    float* __restrict__ out) {
  __shared__ float w3[256];
  const int tid = threadIdx.x;
  w3[tid] = W3[tid];
  __syncthreads();
  const int p = blockIdx.x * 256 + tid;
  float acc0 = b3[0];
  float acc1 = b3[1];
  const uint4* xr = (const uint4*)(x2 + (size_t)p * 128);
#pragma unroll
  for (int kk = 0; kk < 16; ++kk) {
    uint4 v = xr[kk];
    const int k = kk * 8;
    float x0 = __uint_as_float((v.x & 0xffffu) << 16);
    float x1 = __uint_as_float((v.x >> 16) << 16);
    float x2e = __uint_as_float((v.y & 0xffffu) << 16);
    float x3 = __uint_as_float((v.y >> 16) << 16);
    float x4 = __uint_as_float((v.z & 0xffffu) << 16);
    float x5 = __uint_as_float((v.z >> 16) << 16);
    float x6 = __uint_as_float((v.w & 0xffffu) << 16);
    float x7 = __uint_as_float((v.w >> 16) << 16);
    acc0 += x0 * w3[2 * k + 0];  acc1 += x0 * w3[2 * k + 1];
    acc0 += x1 * w3[2 * k + 2];  acc1 += x1 * w3[2 * k + 3];
    acc0 += x2e * w3[2 * k + 4]; acc1 += x2e * w3[2 * k + 5];
    acc0 += x3 * w3[2 * k + 6];  acc1 += x3 * w3[2 * k + 7];
    acc0 += x4 * w3[2 * k + 8];  acc1 += x4 * w3[2 * k + 9];
    acc0 += x5 * w3[2 * k + 10]; acc1 += x5 * w3[2 * k + 11];
    acc0 += x6 * w3[2 * k + 12]; acc1 += x6 * w3[2 * k + 13];
    acc0 += x7 * w3[2 * k + 14]; acc1 += x7 * w3[2 * k + 15];
  }
  const float qmf = (float)qmask[p];
  const float v0 = (1.f / (1.f + expf(-acc0))) * 8.f + 1.f;
  const float v1 = (1.f / (1.f + expf(-acc1))) * 8.f + 1.f;
  out[p * 2 + 0] = v0 * qmf;   // f32 output
  out[p * 2 + 1] = v1 * qmf;
}

// ---------------------------------------------------------------------------
extern "C" void kernel_launch(void* const* d_in, const int* in_sizes, int n_in,
                              void* d_out, int out_size, void* d_ws,
                              size_t ws_size, hipStream_t stream) {
  const float* hs = (const float*)d_in[0];   // f32 64x512x1024
  const int* spans = (const int*)d_in[1];
  const int* qmask = (const int*)d_in[2];
  const float* W1 = (const float*)d_in[3];   // f32 3072x256
  const float* b1 = (const float*)d_in[4];
  const float* W2 = (const float*)d_in[5];   // f32 256x128
  const float* b2 = (const float*)d_in[6];
  const float* W3 = (const float*)d_in[7];   // f32 128x2
  const float* b3 = (const float*)d_in[8];
  float* out = (float*)d_out;

  const size_t P_BYTES = 134217728;  // 64*512*1024 f32
  const size_t HPAIR_B = 25165824;   // 4096*3072 bf16
  const size_t X1_B = 2097152, X2_B = 1048576;
  const size_t W1T_B = 1572864, W2T_B = 65536;
  const size_t need_prefix = P_BYTES + HPAIR_B + X1_B + X2_B + W1T_B + W2T_B;

  char* ws = (char*)d_ws;
  const bool use_prefix = (ws_size >= need_prefix);
  size_t off = use_prefix ? P_BYTES : 0;
  float* P = (float*)ws;
  unsigned short* hpair = (unsigned short*)(ws + off); off += HPAIR_B;
  unsigned short* x1 = (unsigned short*)(ws + off);    off += X1_B;
  unsigned short* x2 = (unsigned short*)(ws + off);    off += X2_B;
  unsigned short* W1T = (unsigned short*)(ws + off);   off += W1T_B;
  unsigned short* W2T = (unsigned short*)(ws + off);

  transpose_f32_bf16<<<dim3(8, 96), dim3(32, 8), 0, stream>>>(W1, W1T, 3072,
                                                              256);
  transpose_f32_bf16<<<dim3(4, 8), dim3(32, 8), 0, stream>>>(W2, W2T, 256,
                                                             128);
  if (use_prefix) {
    cumsum_kernel<<<256, 256, 0, stream>>>(hs, P);
    pool_from_prefix<<<NPAIR, 256, 0, stream>>>(P, spans, qmask, hpair);
  } else {
    pool_brute<<<NPAIR, 256, 0, stream>>>(hs, spans, qmask, hpair);
  }
  gemm_bt_bias_act<1><<<dim3(64, 4), 256, 0, stream>>>(hpair, W1T, b1, x1,
                                                       NPAIR, 256, 3072);
  gemm_bt_bias_act<1><<<dim3(64, 2), 256, 0, stream>>>(x1, W2T, b2, x2, NPAIR,
                                                       128, 256);
  head_kernel<<<16, 256, 0, stream>>>(x2, W3, b3, qmask, out);
}

// Round 4
// 267.424 us; speedup vs baseline: 1.3484x; 1.3484x over previous
//
#include <hip/hip_runtime.h>
#include <math.h>

// SpanPairVAHead on MI355X (gfx950).
// Dtype map (established rounds 0-3): ALL float tensors f32, spans int
// (32/64 sniffed on device), OUTPUT f32. Internal activations bf16 for MFMA.
//
// R4: pooling = masked MFMA GEMM (mask(128xL) @ hs(LxH) per batch), replacing
// the latency-bound cumsum (124us @ 20% BW, 10% occupancy) + gather.
// hs is read exactly once (H-slices partition columns) -> HBM-stream-bound.
//
// B=64, L=512, H=1024, Q=64, VA_H=256. Pairs = B*Q = 4096.

typedef __attribute__((ext_vector_type(4))) float f32x4;
typedef __attribute__((ext_vector_type(8))) short bf16x8;

#define NPAIR 4096
#define LSEQ 512
#define HDIM 1024

__device__ __forceinline__ unsigned short f2bf(float f) {
  unsigned int x = __float_as_uint(f);
  return (unsigned short)((x + 0x7fffu + ((x >> 16) & 1u)) >> 16);  // RNE
}
__device__ __forceinline__ unsigned int pack2(float lo, float hi) {
  return (unsigned int)f2bf(lo) | ((unsigned int)f2bf(hi) << 16);
}

// ---------------------------------------------------------------------------
// Fused span pooling via MFMA. One block per (batch, 128-col H-slice).
// Rows 0..63 = asp masks, 64..127 = opi masks. A-frags built in registers
// from span compares; B staged f32->bf16 transposed ([n][k]) for ds_read_b128.
// Epilogue: scale sums by 1/count, emit h_pair = [asp | opi | asp*opi] bf16.
// ---------------------------------------------------------------------------
__global__ __launch_bounds__(256, 2) void pool_mfma_kernel(
    const float* __restrict__ hs, const int* __restrict__ spans,
    const int* __restrict__ qmask, unsigned short* __restrict__ hpair) {
  __shared__ __align__(16) unsigned short Bl[128][40];  // [n][k], 16B-aligned rows
  __shared__ float S[128][129];
  __shared__ float scl[128];

  const int b = blockIdx.x >> 3;
  const int n0 = (blockIdx.x & 7) * 128;
  const int tid = threadIdx.x;
  const int lane = tid & 63;
  const int lm = lane & 15, quad = lane >> 4;
  const int wm = (tid >> 6) * 32;  // wave's M-base

  const bool is64 =
      (spans[1] == 0) && (spans[3] == 0) && (spans[5] == 0) && (spans[7] == 0);

  // Span decode for this lane's two A-rows (r and r+16).
  auto span_of = [&](int r, int& s, int& e) {
    const int q = r & 63, t = r >> 6;
    const int idx = (b * 64 + q) * 4 + t * 2;
    s = is64 ? spans[idx * 2] : spans[idx];
    e = is64 ? spans[idx * 2 + 2] : spans[idx + 1];
    if (s < 2) { s = 1; e = 1; }  // invalid -> [SEP]
  };
  int s0, e0, s1, e1;
  span_of(wm + lm, s0, e0);
  span_of(wm + 16 + lm, s1, e1);

  // Per-row output scale (1/count, or 0 for masked quads).
  if (tid < 128) {
    int s, e;
    span_of(tid, s, e);
    const int c = (e >= s) ? (e - s + 1) : 0;  // c==0 -> sum is 0 anyway
    const float sc = 1.f / (float)(c < 1 ? 1 : c);
    scl[tid] = (qmask[b * 64 + (tid & 63)] != 0) ? sc : 0.f;
  }

  f32x4 acc[2][8];
#pragma unroll
  for (int f = 0; f < 2; ++f)
#pragma unroll
    for (int g = 0; g < 8; ++g) acc[f][g] = f32x4{0.f, 0.f, 0.f, 0.f};

  const float* hsb = hs + (size_t)b * (LSEQ * HDIM);
  const int nl = tid & 127;          // staged column
  const int kb = (tid >> 7) * 16;    // k-chunk (0 or 16)

  for (int k0 = 0; k0 < LSEQ; k0 += 32) {
    // Load 16 k-values of one column (coalesced across lanes), convert.
    const float* src = hsb + (size_t)(k0 + kb) * HDIM + n0 + nl;
    unsigned int tmp[8];
#pragma unroll
    for (int i = 0; i < 8; ++i) {
      const float f0 = src[(size_t)(2 * i) * HDIM];
      const float f1 = src[(size_t)(2 * i + 1) * HDIM];
      tmp[i] = pack2(f0, f1);
    }
    __syncthreads();  // previous iteration's B-frag reads complete
    *(uint4*)&Bl[nl][kb] = make_uint4(tmp[0], tmp[1], tmp[2], tmp[3]);
    *(uint4*)&Bl[nl][kb + 8] = make_uint4(tmp[4], tmp[5], tmp[6], tmp[7]);
    __syncthreads();

    // A-frags from span compares (A[m=lane&15][k=quad*8+j]).
    bf16x8 a0, a1;
#pragma unroll
    for (int j = 0; j < 8; ++j) {
      const int k = k0 + quad * 8 + j;
      a0[j] = (short)((k >= s0 && k <= e0) ? 0x3F80 : 0);
      a1[j] = (short)((k >= s1 && k <= e1) ? 0x3F80 : 0);
    }
#pragma unroll
    for (int g = 0; g < 8; ++g) {
      bf16x8 bg = *(const bf16x8*)&Bl[g * 16 + lm][quad * 8];
      acc[0][g] = __builtin_amdgcn_mfma_f32_16x16x32_bf16(a0, bg, acc[0][g], 0, 0, 0);
      acc[1][g] = __builtin_amdgcn_mfma_f32_16x16x32_bf16(a1, bg, acc[1][g], 0, 0, 0);
    }
  }

  // C/D layout (m89): col = lane&15, row = quad*4 + reg.
#pragma unroll
  for (int f = 0; f < 2; ++f)
#pragma unroll
    for (int g = 0; g < 8; ++g)
#pragma unroll
      for (int r = 0; r < 4; ++r)
        S[wm + f * 16 + quad * 4 + r][g * 16 + lm] = acc[f][g][r];
  __syncthreads();

  // Emit h_pair sections. Thread: q = tid>>2, 32-col group = (tid&3)*32.
  const int q = tid >> 2;
  const int cg = (tid & 3) * 32;
  const float sA = scl[q], sO = scl[64 + q];
  unsigned short* dst = hpair + (size_t)(b * 64 + q) * 3072 + n0 + cg;
#pragma unroll
  for (int j4 = 0; j4 < 4; ++j4) {
    float a[8], o[8];
#pragma unroll
    for (int i = 0; i < 8; ++i) {
      a[i] = S[q][cg + j4 * 8 + i] * sA;
      o[i] = S[64 + q][cg + j4 * 8 + i] * sO;
    }
    uint4 wa, wo, wp;
    wa.x = pack2(a[0], a[1]); wa.y = pack2(a[2], a[3]);
    wa.z = pack2(a[4], a[5]); wa.w = pack2(a[6], a[7]);
    wo.x = pack2(o[0], o[1]); wo.y = pack2(o[2], o[3]);
    wo.z = pack2(o[4], o[5]); wo.w = pack2(o[6], o[7]);
    wp.x = pack2(a[0] * o[0], a[1] * o[1]); wp.y = pack2(a[2] * o[2], a[3] * o[3]);
    wp.z = pack2(a[4] * o[4], a[5] * o[5]); wp.w = pack2(a[6] * o[6], a[7] * o[7]);
    *(uint4*)(dst + j4 * 8) = wa;
    *(uint4*)(dst + 1024 + j4 * 8) = wo;
    *(uint4*)(dst + 2048 + j4 * 8) = wp;
  }
}

// ---------------------------------------------------------------------------
// Transpose + f32->bf16 convert: in (R x C) f32 -> out (C x R) bf16.
// ---------------------------------------------------------------------------
__global__ void transpose_f32_bf16(const float* __restrict__ in,
                                   unsigned short* __restrict__ out, int R,
                                   int C) {
  __shared__ float t[32][33];
  const int c0 = blockIdx.x * 32, r0 = blockIdx.y * 32;
  const int x = threadIdx.x, y = threadIdx.y;  // block (32, 8)
#pragma unroll
  for (int i = 0; i < 32; i += 8)
    if (r0 + y + i < R && c0 + x < C)
      t[y + i][x] = in[(size_t)(r0 + y + i) * C + c0 + x];
  __syncthreads();
#pragma unroll
  for (int i = 0; i < 32; i += 8)
    if (c0 + y + i < C && r0 + x < R)
      out[(size_t)(c0 + y + i) * R + r0 + x] = f2bf(t[x][y + i]);
}

// ---------------------------------------------------------------------------
// bf16 MFMA GEMM: C = act(A(MxK) @ Bt(NxK)^T + bias_f32) -> bf16.
// 64x64 tile, BK=32, 4 waves, 2x2 mfma_f32_16x16x32_bf16 per wave.
// ---------------------------------------------------------------------------
template <int ACT>
__global__ __launch_bounds__(256) void gemm_bt_bias_act(
    const unsigned short* __restrict__ A, const unsigned short* __restrict__ Bt,
    const float* __restrict__ bias, unsigned short* __restrict__ C, int M,
    int N, int K) {
  __shared__ __align__(16) unsigned short Al[64][40];
  __shared__ __align__(16) unsigned short Bl[64][40];
  const int bm = blockIdx.x * 64, bn = blockIdx.y * 64;
  const int tid = threadIdx.x;
  const int wave = tid >> 6, lane = tid & 63;
  const int wm = (wave & 1) * 32, wn = (wave >> 1) * 32;
  const int ar = tid >> 2, ac = (tid & 3) * 8;
  const int lm = lane & 15, lk = (lane >> 4) * 8;

  f32x4 acc00 = {0.f, 0.f, 0.f, 0.f}, acc01 = {0.f, 0.f, 0.f, 0.f};
  f32x4 acc10 = {0.f, 0.f, 0.f, 0.f}, acc11 = {0.f, 0.f, 0.f, 0.f};

  const unsigned short* pa = A + (size_t)(bm + ar) * K + ac;
  const unsigned short* pb = Bt + (size_t)(bn + ar) * K + ac;

  for (int k0 = 0; k0 < K; k0 += 32) {
    uint4 va = *(const uint4*)(pa + k0);
    uint4 vb = *(const uint4*)(pb + k0);
    *(uint4*)&Al[ar][ac] = va;
    *(uint4*)&Bl[ar][ac] = vb;
    __syncthreads();
    bf16x8 a0 = *(const bf16x8*)&Al[wm + lm][lk];
    bf16x8 a1 = *(const bf16x8*)&Al[wm + 16 + lm][lk];
    bf16x8 b0 = *(const bf16x8*)&Bl[wn + lm][lk];
    bf16x8 b1 = *(const bf16x8*)&Bl[wn + 16 + lm][lk];
    acc00 = __builtin_amdgcn_mfma_f32_16x16x32_bf16(a0, b0, acc00, 0, 0, 0);
    acc01 = __builtin_amdgcn_mfma_f32_16x16x32_bf16(a0, b1, acc01, 0, 0, 0);
    acc10 = __builtin_amdgcn_mfma_f32_16x16x32_bf16(a1, b0, acc10, 0, 0, 0);
    acc11 = __builtin_amdgcn_mfma_f32_16x16x32_bf16(a1, b1, acc11, 0, 0, 0);
    __syncthreads();
  }

  // C/D layout (m89): col = lane&15, row = (lane>>4)*4 + reg.
  const int r0 = bm + wm + ((lane >> 4) << 2);
  const int c0 = bn + wn + lm;
  const float bs0 = bias[c0];
  const float bs1 = bias[c0 + 16];
  auto emit = [&](f32x4 v, int row0, int col, float bs) {
#pragma unroll
    for (int r = 0; r < 4; ++r) {
      float x = v[r] + bs;
      if (ACT == 1) x = 0.5f * x * (1.f + erff(x * 0.70710678118654752f));
      C[(size_t)(row0 + r) * N + col] = f2bf(x);
    }
  };
  emit(acc00, r0, c0, bs0);
  emit(acc10, r0 + 16, c0, bs0);
  emit(acc01, r0, c0 + 16, bs1);
  emit(acc11, r0 + 16, c0 + 16, bs1);
}

// ---------------------------------------------------------------------------
// Head: x2(4096x128 bf16) @ W3(128x2 f32) + b3 -> sigmoid*8+1 -> *mask -> F32
// ---------------------------------------------------------------------------
__global__ __launch_bounds__(256) void head_kernel(
    const unsigned short* __restrict__ x2, const float* __restrict__ W3,
    const float* __restrict__ b3, const int* __restrict__ qmask,
    float* __restrict__ out) {
  __shared__ float w3[256];
  const int tid = threadIdx.x;
  w3[tid] = W3[tid];
  __syncthreads();
  const int p = blockIdx.x * 256 + tid;
  float acc0 = b3[0];
  float acc1 = b3[1];
  const uint4* xr = (const uint4*)(x2 + (size_t)p * 128);
#pragma unroll
  for (int kk = 0; kk < 16; ++kk) {
    uint4 v = xr[kk];
    const int k = kk * 8;
    float x0 = __uint_as_float((v.x & 0xffffu) << 16);
    float x1 = __uint_as_float((v.x >> 16) << 16);
    float x2e = __uint_as_float((v.y & 0xffffu) << 16);
    float x3 = __uint_as_float((v.y >> 16) << 16);
    float x4 = __uint_as_float((v.z & 0xffffu) << 16);
    float x5 = __uint_as_float((v.z >> 16) << 16);
    float x6 = __uint_as_float((v.w & 0xffffu) << 16);
    float x7 = __uint_as_float((v.w >> 16) << 16);
    acc0 += x0 * w3[2 * k + 0];  acc1 += x0 * w3[2 * k + 1];
    acc0 += x1 * w3[2 * k + 2];  acc1 += x1 * w3[2 * k + 3];
    acc0 += x2e * w3[2 * k + 4]; acc1 += x2e * w3[2 * k + 5];
    acc0 += x3 * w3[2 * k + 6];  acc1 += x3 * w3[2 * k + 7];
    acc0 += x4 * w3[2 * k + 8];  acc1 += x4 * w3[2 * k + 9];
    acc0 += x5 * w3[2 * k + 10]; acc1 += x5 * w3[2 * k + 11];
    acc0 += x6 * w3[2 * k + 12]; acc1 += x6 * w3[2 * k + 13];
    acc0 += x7 * w3[2 * k + 14]; acc1 += x7 * w3[2 * k + 15];
  }
  const float qmf = (float)qmask[p];
  const float v0 = (1.f / (1.f + expf(-acc0))) * 8.f + 1.f;
  const float v1 = (1.f / (1.f + expf(-acc1))) * 8.f + 1.f;
  out[p * 2 + 0] = v0 * qmf;   // f32 output
  out[p * 2 + 1] = v1 * qmf;
}

// ---------------------------------------------------------------------------
extern "C" void kernel_launch(void* const* d_in, const int* in_sizes, int n_in,
                              void* d_out, int out_size, void* d_ws,
                              size_t ws_size, hipStream_t stream) {
  const float* hs = (const float*)d_in[0];   // f32 64x512x1024
  const int* spans = (const int*)d_in[1];
  const int* qmask = (const int*)d_in[2];
  const float* W1 = (const float*)d_in[3];   // f32 3072x256
  const float* b1 = (const float*)d_in[4];
  const float* W2 = (const float*)d_in[5];   // f32 256x128
  const float* b2 = (const float*)d_in[6];
  const float* W3 = (const float*)d_in[7];   // f32 128x2
  const float* b3 = (const float*)d_in[8];
  float* out = (float*)d_out;

  const size_t HPAIR_B = 25165824;   // 4096*3072 bf16
  const size_t X1_B = 2097152, X2_B = 1048576;
  const size_t W1T_B = 1572864;

  char* ws = (char*)d_ws;
  size_t off = 0;
  unsigned short* hpair = (unsigned short*)(ws + off); off += HPAIR_B;
  unsigned short* x1 = (unsigned short*)(ws + off);    off += X1_B;
  unsigned short* x2 = (unsigned short*)(ws + off);    off += X2_B;
  unsigned short* W1T = (unsigned short*)(ws + off);   off += W1T_B;
  unsigned short* W2T = (unsigned short*)(ws + off);

  transpose_f32_bf16<<<dim3(8, 96), dim3(32, 8), 0, stream>>>(W1, W1T, 3072,
                                                              256);
  transpose_f32_bf16<<<dim3(4, 8), dim3(32, 8), 0, stream>>>(W2, W2T, 256,
                                                             128);
  pool_mfma_kernel<<<512, 256, 0, stream>>>(hs, spans, qmask, hpair);
  gemm_bt_bias_act<1><<<dim3(64, 4), 256, 0, stream>>>(hpair, W1T, b1, x1,
                                                       NPAIR, 256, 3072);
  gemm_bt_bias_act<1><<<dim3(64, 2), 256, 0, stream>>>(x1, W2T, b2, x2, NPAIR,
                                                       128, 256);
  head_kernel<<<16, 256, 0, stream>>>(x2, W3, b3, qmask, out);
}

// Round 5
// 250.832 us; speedup vs baseline: 1.4376x; 1.0661x over previous
//
#include <hip/hip_runtime.h>
#include <math.h>

// SpanPairVAHead on MI355X (gfx950).
// Dtype map (established rounds 0-3): ALL float tensors f32, spans int
// (32/64 sniffed on device), OUTPUT f32. Internal activations bf16 for MFMA.
//
// R5: (1) gemm2+head fused; (2) split-K x2 GEMM1 (1->2 blocks/CU) + fused
// bias/gelu reduce; (3) pool double-buffered, 1 barrier/iter, LDS union;
// (4) single transpose launch. 5 launches total.
//
// B=64, L=512, H=1024, Q=64, VA_H=256. Pairs = B*Q = 4096.

typedef __attribute__((ext_vector_type(4))) float f32x4;
typedef __attribute__((ext_vector_type(8))) short bf16x8;

#define NPAIR 4096
#define LSEQ 512
#define HDIM 1024

__device__ __forceinline__ unsigned short f2bf(float f) {
  unsigned int x = __float_as_uint(f);
  return (unsigned short)((x + 0x7fffu + ((x >> 16) & 1u)) >> 16);  // RNE
}
__device__ __forceinline__ unsigned int pack2(float lo, float hi) {
  return (unsigned int)f2bf(lo) | ((unsigned int)f2bf(hi) << 16);
}
__device__ __forceinline__ float gelu(float x) {
  return 0.5f * x * (1.f + erff(x * 0.70710678118654752f));
}

// ---------------------------------------------------------------------------
// Fused span pooling via MFMA. One block per (batch, 128-col H-slice).
// Rows 0..63 = asp masks, 64..127 = opi masks. A-frags from span compares in
// registers; B staged f32->bf16 transposed ([n][k]). Double-buffered Bl,
// ONE barrier per k-iter; epilogue S[128][129] unions with Bl (LDS 66.5KB).
// ---------------------------------------------------------------------------
__global__ __launch_bounds__(256, 2) void pool_mfma_kernel(
    const float* __restrict__ hs, const int* __restrict__ spans,
    const int* __restrict__ qmask, unsigned short* __restrict__ hpair) {
  __shared__ __align__(16) unsigned char smem[66048];  // max(2*128*40*2, 128*129*4)
  __shared__ float scl[128];
  typedef unsigned short BlT[128][40];
  BlT* Bl = (BlT*)smem;                    // Bl[2][128][40]
  float(*S)[129] = (float(*)[129])smem;    // S[128][129] (epilogue only)

  const int b = blockIdx.x >> 3;
  const int n0 = (blockIdx.x & 7) * 128;
  const int tid = threadIdx.x;
  const int lane = tid & 63;
  const int lm = lane & 15, quad = lane >> 4;
  const int wm = (tid >> 6) * 32;  // wave's M-base

  const bool is64 =
      (spans[1] == 0) && (spans[3] == 0) && (spans[5] == 0) && (spans[7] == 0);

  auto span_of = [&](int r, int& s, int& e) {
    const int q = r & 63, t = r >> 6;
    const int idx = (b * 64 + q) * 4 + t * 2;
    s = is64 ? spans[idx * 2] : spans[idx];
    e = is64 ? spans[idx * 2 + 2] : spans[idx + 1];
    if (s < 2) { s = 1; e = 1; }  // invalid -> [SEP]
  };
  int s0, e0, s1, e1;
  span_of(wm + lm, s0, e0);
  span_of(wm + 16 + lm, s1, e1);

  if (tid < 128) {
    int s, e;
    span_of(tid, s, e);
    const int c = (e >= s) ? (e - s + 1) : 0;
    const float sc = 1.f / (float)(c < 1 ? 1 : c);
    scl[tid] = (qmask[b * 64 + (tid & 63)] != 0) ? sc : 0.f;
  }

  f32x4 acc[2][8];
#pragma unroll
  for (int f = 0; f < 2; ++f)
#pragma unroll
    for (int g = 0; g < 8; ++g) acc[f][g] = f32x4{0.f, 0.f, 0.f, 0.f};

  const float* hsb = hs + (size_t)b * (LSEQ * HDIM);
  const int nl = tid & 127;        // staged column
  const int kb = (tid >> 7) * 16;  // k-chunk (0 or 16)

  auto load16 = [&](int kbase, unsigned int (&tmp)[8]) {
    const float* src = hsb + (size_t)(kbase + kb) * HDIM + n0 + nl;
#pragma unroll
    for (int i = 0; i < 8; ++i) {
      const float f0 = src[(size_t)(2 * i) * HDIM];
      const float f1 = src[(size_t)(2 * i + 1) * HDIM];
      tmp[i] = pack2(f0, f1);
    }
  };

  // Prologue: stage k0=0 into buffer 0.
  unsigned int tmp[8];
  load16(0, tmp);
  *(uint4*)&Bl[0][nl][kb] = make_uint4(tmp[0], tmp[1], tmp[2], tmp[3]);
  *(uint4*)&Bl[0][nl][kb + 8] = make_uint4(tmp[4], tmp[5], tmp[6], tmp[7]);

  for (int it = 0; it < 16; ++it) {
    const int k0 = it * 32;
    __syncthreads();  // buf[it&1] ready; prior reads of buf[(it+1)&1] done
    if (it < 15) load16(k0 + 32, tmp);

    bf16x8 a0, a1;
#pragma unroll
    for (int j = 0; j < 8; ++j) {
      const int k = k0 + quad * 8 + j;
      a0[j] = (short)((k >= s0 && k <= e0) ? 0x3F80 : 0);
      a1[j] = (short)((k >= s1 && k <= e1) ? 0x3F80 : 0);
    }
    const BlT& Bc = Bl[it & 1];
#pragma unroll
    for (int g = 0; g < 8; ++g) {
      bf16x8 bg = *(const bf16x8*)&Bc[g * 16 + lm][quad * 8];
      acc[0][g] = __builtin_amdgcn_mfma_f32_16x16x32_bf16(a0, bg, acc[0][g], 0, 0, 0);
      acc[1][g] = __builtin_amdgcn_mfma_f32_16x16x32_bf16(a1, bg, acc[1][g], 0, 0, 0);
    }
    if (it < 15) {
      BlT& Bn = Bl[(it + 1) & 1];
      *(uint4*)&Bn[nl][kb] = make_uint4(tmp[0], tmp[1], tmp[2], tmp[3]);
      *(uint4*)&Bn[nl][kb + 8] = make_uint4(tmp[4], tmp[5], tmp[6], tmp[7]);
    }
  }

  __syncthreads();  // all MFMA LDS reads done before S overwrites Bl
  // C/D layout (m89): col = lane&15, row = quad*4 + reg.
#pragma unroll
  for (int f = 0; f < 2; ++f)
#pragma unroll
    for (int g = 0; g < 8; ++g)
#pragma unroll
      for (int r = 0; r < 4; ++r)
        S[wm + f * 16 + quad * 4 + r][g * 16 + lm] = acc[f][g][r];
  __syncthreads();

  const int q = tid >> 2;
  const int cg = (tid & 3) * 32;
  const float sA = scl[q], sO = scl[64 + q];
  unsigned short* dst = hpair + (size_t)(b * 64 + q) * 3072 + n0 + cg;
#pragma unroll
  for (int j4 = 0; j4 < 4; ++j4) {
    float a[8], o[8];
#pragma unroll
    for (int i = 0; i < 8; ++i) {
      a[i] = S[q][cg + j4 * 8 + i] * sA;
      o[i] = S[64 + q][cg + j4 * 8 + i] * sO;
    }
    uint4 wa, wo, wp;
    wa.x = pack2(a[0], a[1]); wa.y = pack2(a[2], a[3]);
    wa.z = pack2(a[4], a[5]); wa.w = pack2(a[6], a[7]);
    wo.x = pack2(o[0], o[1]); wo.y = pack2(o[2], o[3]);
    wo.z = pack2(o[4], o[5]); wo.w = pack2(o[6], o[7]);
    wp.x = pack2(a[0] * o[0], a[1] * o[1]); wp.y = pack2(a[2] * o[2], a[3] * o[3]);
    wp.z = pack2(a[4] * o[4], a[5] * o[5]); wp.w = pack2(a[6] * o[6], a[7] * o[7]);
    *(uint4*)(dst + j4 * 8) = wa;
    *(uint4*)(dst + 1024 + j4 * 8) = wo;
    *(uint4*)(dst + 2048 + j4 * 8) = wp;
  }
}

// ---------------------------------------------------------------------------
// Both weight transposes in one launch. Blocks 0..767: W1 (3072x256);
// 768..799: W2 (256x128). f32 in -> bf16 out, transposed.
// ---------------------------------------------------------------------------
__global__ void transpose_two(const float* __restrict__ W1,
                              unsigned short* __restrict__ W1T,
                              const float* __restrict__ W2,
                              unsigned short* __restrict__ W2T) {
  __shared__ float t[32][33];
  const float* in;
  unsigned short* out;
  int R, C, c0, r0;
  int blk = blockIdx.x;
  if (blk < 768) {
    in = W1; out = W1T; R = 3072; C = 256;
    c0 = (blk & 7) * 32; r0 = (blk >> 3) * 32;
  } else {
    blk -= 768;
    in = W2; out = W2T; R = 256; C = 128;
    c0 = (blk & 3) * 32; r0 = (blk >> 2) * 32;
  }
  const int x = threadIdx.x, y = threadIdx.y;  // (32, 8)
#pragma unroll
  for (int i = 0; i < 32; i += 8)
    t[y + i][x] = in[(size_t)(r0 + y + i) * C + c0 + x];
  __syncthreads();
#pragma unroll
  for (int i = 0; i < 32; i += 8)
    out[(size_t)(c0 + y + i) * R + r0 + x] = f2bf(t[x][y + i]);
}

// ---------------------------------------------------------------------------
// Split-K GEMM1 partial: P[z] = A(MxKh slice) @ Bt^T, raw f32 sums.
// 64x64 tile, BK=32, 4 waves, 2x2 mfma. z = blockIdx.z selects K-half.
// ---------------------------------------------------------------------------
__global__ __launch_bounds__(256) void gemm_bt_partial(
    const unsigned short* __restrict__ A, const unsigned short* __restrict__ Bt,
    float* __restrict__ P, int M, int N, int K, int KH) {
  __shared__ __align__(16) unsigned short Al[64][40];
  __shared__ __align__(16) unsigned short Bl[64][40];
  const int bm = blockIdx.x * 64, bn = blockIdx.y * 64;
  const int kz = blockIdx.z * KH;
  const int tid = threadIdx.x;
  const int wave = tid >> 6, lane = tid & 63;
  const int wm = (wave & 1) * 32, wn = (wave >> 1) * 32;
  const int ar = tid >> 2, ac = (tid & 3) * 8;
  const int lm = lane & 15, lk = (lane >> 4) * 8;

  f32x4 acc00 = {0.f, 0.f, 0.f, 0.f}, acc01 = {0.f, 0.f, 0.f, 0.f};
  f32x4 acc10 = {0.f, 0.f, 0.f, 0.f}, acc11 = {0.f, 0.f, 0.f, 0.f};

  const unsigned short* pa = A + (size_t)(bm + ar) * K + kz + ac;
  const unsigned short* pb = Bt + (size_t)(bn + ar) * K + kz + ac;

  for (int k0 = 0; k0 < KH; k0 += 32) {
    uint4 va = *(const uint4*)(pa + k0);
    uint4 vb = *(const uint4*)(pb + k0);
    *(uint4*)&Al[ar][ac] = va;
    *(uint4*)&Bl[ar][ac] = vb;
    __syncthreads();
    bf16x8 a0 = *(const bf16x8*)&Al[wm + lm][lk];
    bf16x8 a1 = *(const bf16x8*)&Al[wm + 16 + lm][lk];
    bf16x8 b0 = *(const bf16x8*)&Bl[wn + lm][lk];
    bf16x8 b1 = *(const bf16x8*)&Bl[wn + 16 + lm][lk];
    acc00 = __builtin_amdgcn_mfma_f32_16x16x32_bf16(a0, b0, acc00, 0, 0, 0);
    acc01 = __builtin_amdgcn_mfma_f32_16x16x32_bf16(a0, b1, acc01, 0, 0, 0);
    acc10 = __builtin_amdgcn_mfma_f32_16x16x32_bf16(a1, b0, acc10, 0, 0, 0);
    acc11 = __builtin_amdgcn_mfma_f32_16x16x32_bf16(a1, b1, acc11, 0, 0, 0);
    __syncthreads();
  }

  float* Pz = P + (size_t)blockIdx.z * M * N;
  const int r0 = bm + wm + ((lane >> 4) << 2);
  const int c0 = bn + wn + lm;
  auto emit = [&](f32x4 v, int row0, int col) {
#pragma unroll
    for (int r = 0; r < 4; ++r) Pz[(size_t)(row0 + r) * N + col] = v[r];
  };
  emit(acc00, r0, c0);
  emit(acc10, r0 + 16, c0);
  emit(acc01, r0, c0 + 16);
  emit(acc11, r0 + 16, c0 + 16);
}

// ---------------------------------------------------------------------------
// Reduce split-K partials + bias + gelu -> x1 bf16. 4096x256 elements.
// ---------------------------------------------------------------------------
__global__ __launch_bounds__(256) void reduce_bias_gelu(
    const float* __restrict__ P, const float* __restrict__ bias,
    unsigned short* __restrict__ X) {
  const int t = blockIdx.x * 256 + threadIdx.x;  // 0..262143
  const int e = t * 4;
  float4 p0 = *(const float4*)(P + e);
  float4 p1 = *(const float4*)(P + (size_t)NPAIR * 256 + e);
  float4 bs = *(const float4*)(bias + (e & 255));
  const float v0 = gelu(p0.x + p1.x + bs.x);
  const float v1 = gelu(p0.y + p1.y + bs.y);
  const float v2 = gelu(p0.z + p1.z + bs.z);
  const float v3 = gelu(p0.w + p1.w + bs.w);
  uint2 w;
  w.x = pack2(v0, v1);
  w.y = pack2(v2, v3);
  *(uint2*)(X + e) = w;
}

// ---------------------------------------------------------------------------
// Fused GEMM2 + head. Block = 64 rows x full N=128, K=256.
// x2 = gelu(x1 @ W2T^T + b2) -> LDS; then per-row 2-wide head dot with W3,
// sigmoid*8+1, *qmask -> f32 out. 4 waves: wave (wm 0/32, wn 0/64), 2x4 accs.
// ---------------------------------------------------------------------------
__global__ __launch_bounds__(256) void gemm2_head_kernel(
    const unsigned short* __restrict__ A, const unsigned short* __restrict__ Bt,
    const float* __restrict__ b2, const float* __restrict__ W3,
    const float* __restrict__ b3, const int* __restrict__ qmask,
    float* __restrict__ out) {
  __shared__ __align__(16) unsigned short Al[64][40];
  __shared__ __align__(16) unsigned short Bl[128][40];
  __shared__ float S2[64][129];
  __shared__ float w3[256];

  const int bm = blockIdx.x * 64;
  const int tid = threadIdx.x;
  const int wave = tid >> 6, lane = tid & 63;
  const int wm = (wave & 1) * 32, wn = (wave >> 1) * 64;
  const int ar = tid >> 2, ac = (tid & 3) * 8;   // A staging
  const int br = tid >> 1, bc = (tid & 1) * 16;  // B staging (2x uint4)
  const int lm = lane & 15, quad = lane >> 4;

  w3[tid] = W3[tid];

  f32x4 acc[2][4];
#pragma unroll
  for (int f = 0; f < 2; ++f)
#pragma unroll
    for (int g = 0; g < 4; ++g) acc[f][g] = f32x4{0.f, 0.f, 0.f, 0.f};

  const unsigned short* pa = A + (size_t)(bm + ar) * 256 + ac;
  const unsigned short* pb = Bt + (size_t)br * 256 + bc;

  for (int k0 = 0; k0 < 256; k0 += 32) {
    uint4 va = *(const uint4*)(pa + k0);
    uint4 vb0 = *(const uint4*)(pb + k0);
    uint4 vb1 = *(const uint4*)(pb + k0 + 8);
    *(uint4*)&Al[ar][ac] = va;
    *(uint4*)&Bl[br][bc] = vb0;
    *(uint4*)&Bl[br][bc + 8] = vb1;
    __syncthreads();
    bf16x8 a0 = *(const bf16x8*)&Al[wm + lm][quad * 8];
    bf16x8 a1 = *(const bf16x8*)&Al[wm + 16 + lm][quad * 8];
#pragma unroll
    for (int g = 0; g < 4; ++g) {
      bf16x8 bg = *(const bf16x8*)&Bl[wn + g * 16 + lm][quad * 8];
      acc[0][g] = __builtin_amdgcn_mfma_f32_16x16x32_bf16(a0, bg, acc[0][g], 0, 0, 0);
      acc[1][g] = __builtin_amdgcn_mfma_f32_16x16x32_bf16(a1, bg, acc[1][g], 0, 0, 0);
    }
    __syncthreads();
  }

  // gelu + deposit x2 tile into S2. C/D: col = lane&15, row = quad*4+reg.
#pragma unroll
  for (int f = 0; f < 2; ++f)
#pragma unroll
    for (int g = 0; g < 4; ++g) {
      const int col = wn + g * 16 + lm;
#pragma unroll
      for (int r = 0; r < 4; ++r) {
        const int row = wm + f * 16 + quad * 4 + r;
        S2[row][col] = gelu(acc[f][g][r] + b2[col]);
      }
    }
  __syncthreads();

  // Head: threads 0..127, row = t>>1, o = t&1.
  if (tid < 128) {
    const int row = tid >> 1, o = tid & 1;
    float a = b3[o];
#pragma unroll 8
    for (int c = 0; c < 128; ++c) a += S2[row][c] * w3[c * 2 + o];
    const int pair = bm + row;
    const float qmf = (float)qmask[pair];
    out[pair * 2 + o] = ((1.f / (1.f + expf(-a))) * 8.f + 1.f) * qmf;
  }
}

// ---------------------------------------------------------------------------
extern "C" void kernel_launch(void* const* d_in, const int* in_sizes, int n_in,
                              void* d_out, int out_size, void* d_ws,
                              size_t ws_size, hipStream_t stream) {
  const float* hs = (const float*)d_in[0];   // f32 64x512x1024
  const int* spans = (const int*)d_in[1];
  const int* qmask = (const int*)d_in[2];
  const float* W1 = (const float*)d_in[3];   // f32 3072x256
  const float* b1 = (const float*)d_in[4];
  const float* W2 = (const float*)d_in[5];   // f32 256x128
  const float* b2 = (const float*)d_in[6];
  const float* W3 = (const float*)d_in[7];   // f32 128x2
  const float* b3 = (const float*)d_in[8];
  float* out = (float*)d_out;

  const size_t HPAIR_B = 25165824;          // 4096*3072 bf16
  const size_t X1_B = 2097152;              // 4096*256 bf16
  const size_t P_B = 2 * 4194304;           // 2 x 4096*256 f32
  const size_t W1T_B = 1572864;

  char* ws = (char*)d_ws;
  size_t off = 0;
  unsigned short* hpair = (unsigned short*)(ws + off); off += HPAIR_B;
  unsigned short* x1 = (unsigned short*)(ws + off);    off += X1_B;
  float* P = (float*)(ws + off);                       off += P_B;
  unsigned short* W1T = (unsigned short*)(ws + off);   off += W1T_B;
  unsigned short* W2T = (unsigned short*)(ws + off);

  transpose_two<<<800, dim3(32, 8), 0, stream>>>(W1, W1T, W2, W2T);
  pool_mfma_kernel<<<512, 256, 0, stream>>>(hs, spans, qmask, hpair);
  gemm_bt_partial<<<dim3(64, 4, 2), 256, 0, stream>>>(hpair, W1T, P, NPAIR,
                                                      256, 3072, 1536);
  reduce_bias_gelu<<<1024, 256, 0, stream>>>(P, b1, x1);
  gemm2_head_kernel<<<64, 256, 0, stream>>>(x1, W2T, b2, W3, b3, qmask, out);
}